// Round 2
// baseline (1450.037 us; speedup 1.0000x reference)
//
#include <hip/hip_runtime.h>
#include <stdint.h>

typedef __attribute__((ext_vector_type(8))) short bf16x8;
typedef __attribute__((ext_vector_type(4))) float f32x4;

// ---- bf16 helpers: round-half-up pack (err <= 0.5 ulp, ~2.5 inst/elem) ----
__device__ __forceinline__ uint32_t bfpair(float a, float b) {
    union { float f; uint32_t u; } ca, cb; ca.f = a; cb.f = b;
    return ((ca.u + 0x8000u) >> 16) | ((cb.u + 0x8000u) & 0xFFFF0000u);
}
__device__ __forceinline__ bf16x8 pack2(float4 a, float4 b) {
    union { bf16x8 v; uint32_t u[4]; } r;
    r.u[0] = bfpair(a.x, a.y); r.u[1] = bfpair(a.z, a.w);
    r.u[2] = bfpair(b.x, b.y); r.u[3] = bfpair(b.z, b.w);
    return r.v;
}
__device__ __forceinline__ float bf2f(short s) {
    union { uint32_t u; float f; } c; c.u = ((uint32_t)(uint16_t)s) << 16; return c.f;
}
__device__ __forceinline__ bf16x8 addpack(bf16x8 ib, float4 a, float4 b) {
    float4 x, y;
    x.x = bf2f(ib[0]) + a.x; x.y = bf2f(ib[1]) + a.y;
    x.z = bf2f(ib[2]) + a.z; x.w = bf2f(ib[3]) + a.w;
    y.x = bf2f(ib[4]) + b.x; y.y = bf2f(ib[5]) + b.y;
    y.z = bf2f(ib[6]) + b.z; y.w = bf2f(ib[7]) + b.w;
    return pack2(x, y);
}
__device__ __forceinline__ float tanh_fast(float x) {
    float e = __expf(2.0f * x);
    return 1.0f - 2.0f / (e + 1.0f);
}
#define MFMA16(a, b, c) __builtin_amdgcn_mfma_f32_16x16x32_bf16((a), (b), (c), 0, 0, 0)

// =========================================================================
// Kernel 1: q = tanh(user_emb @ Wq^T + bq) -> q_ws ; bk' = bk + Wk@attr
// =========================================================================
__global__ void finerec_prep(
    const float* __restrict__ user_emb, const float* __restrict__ attr,
    const float* __restrict__ Wq, const float* __restrict__ bq,
    const float* __restrict__ Wk, const float* __restrict__ bk,
    float* __restrict__ q_ws, float* __restrict__ bkp_ws, int U)
{
    if (blockIdx.x == gridDim.x - 1) {   // bias-fold block: bk' = bk + Wk @ attr
        int n = threadIdx.x;
        if (n < 128) {
            const float* wr = Wk + n * 128;
            float s = bk[n];
            for (int k = 0; k < 128; k += 4) {
                float4 w4 = *(const float4*)(wr + k);
                float4 a4 = *(const float4*)(attr + k);
                s += w4.x * a4.x + w4.y * a4.y + w4.z * a4.z + w4.w * a4.w;
            }
            bkp_ws[n] = s;
        }
        return;
    }
    const int tid = threadIdx.x, wv = tid >> 6, lane = tid & 63;
    const int l15 = lane & 15, quad = lane >> 4;
    const int u0 = (blockIdx.x * 4 + wv) * 16;   // 16 users per wave
    int ur = u0 + l15; if (ur >= U) ur = U - 1;
    const float* up = user_emb + (size_t)ur * 128 + quad * 8;
    bf16x8 af[4];
#pragma unroll
    for (int ks = 0; ks < 4; ++ks)
        af[ks] = pack2(*(const float4*)(up + ks * 32), *(const float4*)(up + ks * 32 + 4));
#pragma unroll
    for (int nt = 0; nt < 8; ++nt) {
        const int n = nt * 16 + l15;
        const float* wp = Wq + n * 128 + quad * 8;
        f32x4 acc = {0, 0, 0, 0};
#pragma unroll
        for (int ks = 0; ks < 4; ++ks) {
            bf16x8 bf = pack2(*(const float4*)(wp + ks * 32), *(const float4*)(wp + ks * 32 + 4));
            acc = MFMA16(af[ks], bf, acc);
        }
        const float bqv = bq[n];
#pragma unroll
        for (int r = 0; r < 4; ++r) {   // C: col = lane&15, row = quad*4+r
            int row = u0 + quad * 4 + r;
            if (row < U) q_ws[row * 128 + nt * 16 + l15] = tanh_fast(acc[r] + bqv);
        }
    }
}

// =========================================================================
// Kernel 2: one user per wave, barrier-free after LDS weight fill.
// Streams: gather item -> K MFMAs -> w (shuffle reduce, mask) ->
//          item+opin -> V MFMAs -> o += w*tanh(V). 2 row-pairs of 32 rows.
// =========================================================================
__global__ __launch_bounds__(512, 4) void finerec_main(
    const float* __restrict__ item_table, const float* __restrict__ opin_table,
    const float* __restrict__ bv,
    const float* __restrict__ Wk, const float* __restrict__ Wv,
    const int* __restrict__ item_seqs, const int* __restrict__ opin_seqs,
    const float* __restrict__ q_ws, const float* __restrict__ bkp_ws,
    float* __restrict__ out, int U, int L)
{
    __shared__ __align__(16) short wlds[32768];   // Wk (2048 chunks) + Wv (2048), 16B chunks, XOR-swizzled
    __shared__ __align__(16) int its_lds[512];
    __shared__ __align__(16) int ots_lds[512];

    const int tid = threadIdx.x;
    const int wv = tid >> 6, lane = tid & 63, l15 = lane & 15, quad = lane >> 4;

    // ---- stage Wk, Wv as bf16 fragment chunks (swizzle col c ^= row&15) ----
#pragma unroll
    for (int g0 = 0; g0 < 4096; g0 += 512) {
        const int g = g0 + tid;
        const int mat = g >> 11, gg = g & 2047, r = gg >> 4, c = gg & 15;
        const float* src = (mat ? Wv : Wk) + r * 128 + c * 8;
        float4 A = *(const float4*)src, B = *(const float4*)(src + 4);
        ((bf16x8*)wlds)[(mat << 11) + (r << 4) + (c ^ (r & 15))] = pack2(A, B);
    }

    const int u = blockIdx.x * 8 + wv;
    if (u < U) {   // stage this wave's indices (intra-wave use only)
        int vi = 0, vo = 0;
        if (lane < L) { vi = item_seqs[u * L + lane]; vo = opin_seqs[u * L + lane]; }
        its_lds[wv * 64 + lane] = vi;
        ots_lds[wv * 64 + lane] = vo;
    }
    __syncthreads();   // the ONLY block barrier
    if (u >= U) return;

    float qf[8], bkpf[8], bvf[8];
#pragma unroll
    for (int nt = 0; nt < 8; ++nt) {
        qf[nt]   = q_ws[u * 128 + nt * 16 + l15];
        bkpf[nt] = bkp_ws[nt * 16 + l15];
        bvf[nt]  = bv[nt * 16 + l15];
    }
    float o[8] = {0, 0, 0, 0, 0, 0, 0, 0};
    const int ib = wv * 64;

#pragma unroll
    for (int mp = 0; mp < 2; ++mp) {
        const int r0 = mp * 32;
        const int idx0 = its_lds[ib + r0 + l15];
        const int idx1 = its_lds[ib + r0 + 16 + l15];
        const float* p0 = item_table + (size_t)idx0 * 128 + quad * 8;
        const float* p1 = item_table + (size_t)idx1 * 128 + quad * 8;
        bf16x8 a0[4], a1[4];   // item A-frags: row = lane&15, k = quad*8+j (+32*ks)
#pragma unroll
        for (int ks = 0; ks < 4; ++ks) {
            a0[ks] = pack2(*(const float4*)(p0 + ks * 32), *(const float4*)(p0 + ks * 32 + 4));
            a1[ks] = pack2(*(const float4*)(p1 + ks * 32), *(const float4*)(p1 + ks * 32 + 4));
        }
        // ---- K pass: attr folded into bk' -> k_in is just item ----
        float w0[4] = {0, 0, 0, 0}, w1[4] = {0, 0, 0, 0};
#pragma unroll
        for (int nt = 0; nt < 8; ++nt) {
            f32x4 c0 = {0, 0, 0, 0}, c1 = {0, 0, 0, 0};
#pragma unroll
            for (int ks = 0; ks < 4; ++ks) {
                const int n = nt * 16 + l15, c = ks * 4 + quad;
                bf16x8 wf = ((const bf16x8*)wlds)[(n << 4) + (c ^ (n & 15))];
                c0 = MFMA16(a0[ks], wf, c0);
                c1 = MFMA16(a1[ks], wf, c1);
            }
#pragma unroll
            for (int r = 0; r < 4; ++r) {
                w0[r] += qf[nt] * tanh_fast(c0[r] + bkpf[nt]);
                w1[r] += qf[nt] * tanh_fast(c1[r] + bkpf[nt]);
            }
        }
        // ---- w: reduce over cols (lanes 0-15 within quad) + padding mask ----
        int4 mm0 = *(const int4*)(its_lds + ib + r0 + quad * 4);
        int4 mm1 = *(const int4*)(its_lds + ib + r0 + 16 + quad * 4);
        int ma0[4] = {mm0.x, mm0.y, mm0.z, mm0.w};
        int ma1[4] = {mm1.x, mm1.y, mm1.z, mm1.w};
#pragma unroll
        for (int r = 0; r < 4; ++r) {
            float s0 = w0[r], s1 = w1[r];
            s0 += __shfl_xor(s0, 1); s0 += __shfl_xor(s0, 2);
            s0 += __shfl_xor(s0, 4); s0 += __shfl_xor(s0, 8);
            s1 += __shfl_xor(s1, 1); s1 += __shfl_xor(s1, 2);
            s1 += __shfl_xor(s1, 4); s1 += __shfl_xor(s1, 8);
            w0[r] = (ma0[r] > 0) ? s0 : 0.0f;   // row = r0 + quad*4 + r
            w1[r] = (ma1[r] > 0) ? s1 : 0.0f;   // row = r0 + 16 + quad*4 + r
        }
        // ---- build v_in = item + opin (reuse item frags, no re-gather) ----
        const int od0 = ots_lds[ib + r0 + l15];
        const int od1 = ots_lds[ib + r0 + 16 + l15];
        const float* o0p = opin_table + (size_t)od0 * 128 + quad * 8;
        const float* o1p = opin_table + (size_t)od1 * 128 + quad * 8;
#pragma unroll
        for (int ks = 0; ks < 4; ++ks) {
            a0[ks] = addpack(a0[ks], *(const float4*)(o0p + ks * 32), *(const float4*)(o0p + ks * 32 + 4));
            a1[ks] = addpack(a1[ks], *(const float4*)(o1p + ks * 32), *(const float4*)(o1p + ks * 32 + 4));
        }
        // ---- V pass + weighted aggregation ----
#pragma unroll
        for (int nt = 0; nt < 8; ++nt) {
            f32x4 c0 = {0, 0, 0, 0}, c1 = {0, 0, 0, 0};
#pragma unroll
            for (int ks = 0; ks < 4; ++ks) {
                const int n = nt * 16 + l15, c = ks * 4 + quad;
                bf16x8 wf = ((const bf16x8*)wlds)[2048 + (n << 4) + (c ^ (n & 15))];
                c0 = MFMA16(a0[ks], wf, c0);
                c1 = MFMA16(a1[ks], wf, c1);
            }
            float acc = 0.0f;
#pragma unroll
            for (int r = 0; r < 4; ++r) {
                acc += w0[r] * tanh_fast(c0[r] + bvf[nt]);
                acc += w1[r] * tanh_fast(c1[r] + bvf[nt]);
            }
            o[nt] += acc;
        }
    }
    // ---- reduce o over the 4 row-quads; every lane ends with full sums ----
#pragma unroll
    for (int nt = 0; nt < 8; ++nt) {
        o[nt] += __shfl_xor(o[nt], 16);
        o[nt] += __shfl_xor(o[nt], 32);
    }
    float s0, s1;
    if (quad == 0)      { s0 = o[0]; s1 = o[1]; }
    else if (quad == 1) { s0 = o[2]; s1 = o[3]; }
    else if (quad == 2) { s0 = o[4]; s1 = o[5]; }
    else                { s0 = o[6]; s1 = o[7]; }
    out[u * 128 + (quad * 2 + 0) * 16 + l15] = s0;
    out[u * 128 + (quad * 2 + 1) * 16 + l15] = s1;
}

extern "C" void kernel_launch(void* const* d_in, const int* in_sizes, int n_in,
                              void* d_out, int out_size, void* d_ws, size_t ws_size,
                              hipStream_t stream) {
    const float* item_table = (const float*)d_in[0];
    const float* opin_table = (const float*)d_in[1];
    const float* user_emb   = (const float*)d_in[2];
    const float* attr       = (const float*)d_in[3];
    const float* Wq = (const float*)d_in[4];
    const float* bq = (const float*)d_in[5];
    const float* Wk = (const float*)d_in[6];
    const float* bk = (const float*)d_in[7];
    const float* Wv = (const float*)d_in[8];
    const float* bv = (const float*)d_in[9];
    const int* item_seqs = (const int*)d_in[10];
    const int* opin_seqs = (const int*)d_in[11];
    float* out = (float*)d_out;

    const int U = in_sizes[2] / 128;      // 10000
    const int L = in_sizes[10] / U;       // 50

    float* q_ws   = (float*)d_ws;         // [U,128] fp32
    float* bkp_ws = q_ws + (size_t)U * 128;   // [128]

    finerec_prep<<<(U + 63) / 64 + 1, 256, 0, stream>>>(
        user_emb, attr, Wq, bq, Wk, bk, q_ws, bkp_ws, U);
    finerec_main<<<(U + 7) / 8, 512, 0, stream>>>(
        item_table, opin_table, bv, Wk, Wv, item_seqs, opin_seqs,
        q_ws, bkp_ws, out, U, L);
}

// Round 3
// 723.665 us; speedup vs baseline: 2.0037x; 2.0037x over previous
//
#include <hip/hip_runtime.h>
#include <stdint.h>

typedef __attribute__((ext_vector_type(8))) short bf16x8;
typedef __attribute__((ext_vector_type(4))) float f32x4;

// ---- bf16 helpers: round-half-up pack (err <= 0.5 ulp) ----
__device__ __forceinline__ uint32_t bfpair(float a, float b) {
    union { float f; uint32_t u; } ca, cb; ca.f = a; cb.f = b;
    return ((ca.u + 0x8000u) >> 16) | ((cb.u + 0x8000u) & 0xFFFF0000u);
}
__device__ __forceinline__ bf16x8 pack2(float4 a, float4 b) {
    union { bf16x8 v; uint32_t u[4]; } r;
    r.u[0] = bfpair(a.x, a.y); r.u[1] = bfpair(a.z, a.w);
    r.u[2] = bfpair(b.x, b.y); r.u[3] = bfpair(b.z, b.w);
    return r.v;
}
__device__ __forceinline__ float bf2f(short s) {
    union { uint32_t u; float f; } c; c.u = ((uint32_t)(uint16_t)s) << 16; return c.f;
}
__device__ __forceinline__ bf16x8 addpack(bf16x8 ib, float4 a, float4 b) {
    float4 x, y;
    x.x = bf2f(ib[0]) + a.x; x.y = bf2f(ib[1]) + a.y;
    x.z = bf2f(ib[2]) + a.z; x.w = bf2f(ib[3]) + a.w;
    y.x = bf2f(ib[4]) + b.x; y.y = bf2f(ib[5]) + b.y;
    y.z = bf2f(ib[6]) + b.z; y.w = bf2f(ib[7]) + b.w;
    return pack2(x, y);
}
__device__ __forceinline__ float tanh_fast(float x) {
    float e = __expf(2.0f * x);
    return 1.0f - 2.0f / (e + 1.0f);
}
#define MFMA16(a, b, c) __builtin_amdgcn_mfma_f32_16x16x32_bf16((a), (b), (c), 0, 0, 0)

// =========================================================================
// Kernel 1 (prep): q = tanh(user @ Wq^T + bq) -> q_ws ;
//                  bk' = bk + Wk@attr -> bkp_ws ;
//                  Wk,Wv cast to bf16 swizzled fragment chunks -> wf_ws
// =========================================================================
__global__ void finerec_prep(
    const float* __restrict__ user_emb, const float* __restrict__ attr,
    const float* __restrict__ Wq, const float* __restrict__ bq,
    const float* __restrict__ Wk, const float* __restrict__ bk,
    const float* __restrict__ Wv,
    float* __restrict__ q_ws, float* __restrict__ bkp_ws,
    short* __restrict__ wf_ws, int U)
{
    if (blockIdx.x >= gridDim.x - 8) {           // ---- weight cast: 8 blocks x 512 chunks
        const int bi = blockIdx.x - (gridDim.x - 8);
#pragma unroll
        for (int t = 0; t < 2; ++t) {
            const int g = bi * 512 + t * 256 + threadIdx.x;   // 0..4095
            const int mat = g >> 11, gg = g & 2047, r = gg >> 4, c = gg & 15;
            const float* src = (mat ? Wv : Wk) + r * 128 + c * 8;
            ((bf16x8*)wf_ws)[(mat << 11) + (r << 4) + (c ^ (r & 15))] =
                pack2(*(const float4*)src, *(const float4*)(src + 4));
        }
        return;
    }
    if (blockIdx.x == gridDim.x - 9) {           // ---- bias fold: bk' = bk + Wk @ attr
        int n = threadIdx.x;
        if (n < 128) {
            const float* wr = Wk + n * 128;
            float s = bk[n];
            for (int k = 0; k < 128; k += 4) {
                float4 w4 = *(const float4*)(wr + k);
                float4 a4 = *(const float4*)(attr + k);
                s += w4.x * a4.x + w4.y * a4.y + w4.z * a4.z + w4.w * a4.w;
            }
            bkp_ws[n] = s;
        }
        return;
    }
    // ---- q: 64 users per block (16 per wave) ----
    const int tid = threadIdx.x, wv = tid >> 6, lane = tid & 63;
    const int l15 = lane & 15, quad = lane >> 4;
    const int u0 = (blockIdx.x * 4 + wv) * 16;
    int ur = u0 + l15; if (ur >= U) ur = U - 1;
    const float* up = user_emb + (size_t)ur * 128 + quad * 8;
    bf16x8 af[4];
#pragma unroll
    for (int ks = 0; ks < 4; ++ks)
        af[ks] = pack2(*(const float4*)(up + ks * 32), *(const float4*)(up + ks * 32 + 4));
#pragma unroll
    for (int nt = 0; nt < 8; ++nt) {
        const int n = nt * 16 + l15;
        const float* wp = Wq + n * 128 + quad * 8;
        f32x4 acc = {0, 0, 0, 0};
#pragma unroll
        for (int ks = 0; ks < 4; ++ks) {
            bf16x8 bf = pack2(*(const float4*)(wp + ks * 32), *(const float4*)(wp + ks * 32 + 4));
            acc = MFMA16(af[ks], bf, acc);
        }
        const float bqv = bq[n];
#pragma unroll
        for (int r = 0; r < 4; ++r) {            // C: col = lane&15, row = quad*4+r
            int row = u0 + quad * 4 + r;
            if (row < U) q_ws[row * 128 + nt * 16 + l15] = tanh_fast(acc[r] + bqv);
        }
    }
}

// =========================================================================
// Kernel 2 (main): one user per wave per iteration, 2 users/wave,
// barrier-free after the single LDS weight fill.
// =========================================================================
#define UPW 2
__global__ __launch_bounds__(512, 2) void finerec_main(
    const float* __restrict__ item_table, const float* __restrict__ opin_table,
    const float* __restrict__ bv,
    const int* __restrict__ item_seqs, const int* __restrict__ opin_seqs,
    const float* __restrict__ q_ws, const float* __restrict__ bkp_ws,
    const short* __restrict__ wf_ws,
    float* __restrict__ out, int U, int L)
{
    __shared__ __align__(16) short wlds[32768];   // Wk (2048 16B chunks) + Wv (2048), XOR-swizzled
    __shared__ __align__(16) int its_lds[512];
    __shared__ __align__(16) int ots_lds[512];

    const int tid = threadIdx.x;
    const int wv = tid >> 6, lane = tid & 63, l15 = lane & 15, quad = lane >> 4;

    // ---- stage precast weights: straight 16B copy, 8 chunks/thread ----
    const bf16x8* wsrc = (const bf16x8*)wf_ws;
#pragma unroll
    for (int i = 0; i < 8; ++i)
        ((bf16x8*)wlds)[i * 512 + tid] = wsrc[i * 512 + tid];
    __syncthreads();   // the ONLY block barrier

    float bkpf[8], bvf[8];
#pragma unroll
    for (int nt = 0; nt < 8; ++nt) {
        bkpf[nt] = bkp_ws[nt * 16 + l15];
        bvf[nt]  = bv[nt * 16 + l15];
    }
    const int ib = wv * 64;

    for (int iu = 0; iu < UPW; ++iu) {
        const int u = blockIdx.x * (8 * UPW) + wv * UPW + iu;
        if (u >= U) continue;  // wave-uniform, no barriers below

        {   // stage this wave's indices (intra-wave RAW: ordered by lgkmcnt)
            int vi = 0, vo = 0;
            if (lane < L) { vi = item_seqs[u * L + lane]; vo = opin_seqs[u * L + lane]; }
            its_lds[ib + lane] = vi;
            ots_lds[ib + lane] = vo;
        }
        float qf[8];
#pragma unroll
        for (int nt = 0; nt < 8; ++nt) qf[nt] = q_ws[u * 128 + nt * 16 + l15];

        float o[8] = {0, 0, 0, 0, 0, 0, 0, 0};

#pragma unroll
        for (int mp = 0; mp < 2; ++mp) {
            const int r0 = mp * 32;
            const int idx0 = its_lds[ib + r0 + l15];
            const int idx1 = its_lds[ib + r0 + 16 + l15];
            const float* p0 = item_table + (size_t)idx0 * 128 + quad * 8;
            const float* p1 = item_table + (size_t)idx1 * 128 + quad * 8;
            bf16x8 a0[4], a1[4];   // A-frags: row = lane&15, k = quad*8+j (+32*ks)
#pragma unroll
            for (int ks = 0; ks < 4; ++ks) {
                a0[ks] = pack2(*(const float4*)(p0 + ks * 32), *(const float4*)(p0 + ks * 32 + 4));
                a1[ks] = pack2(*(const float4*)(p1 + ks * 32), *(const float4*)(p1 + ks * 32 + 4));
            }
            // ---- K pass (attr folded into bk') ----
            float w0[4] = {0, 0, 0, 0}, w1[4] = {0, 0, 0, 0};
#pragma unroll
            for (int nt = 0; nt < 8; ++nt) {
                f32x4 c0 = {0, 0, 0, 0}, c1 = {0, 0, 0, 0};
#pragma unroll
                for (int ks = 0; ks < 4; ++ks) {
                    const int n = nt * 16 + l15, c = ks * 4 + quad;
                    bf16x8 wf = ((const bf16x8*)wlds)[(n << 4) + (c ^ (n & 15))];
                    c0 = MFMA16(a0[ks], wf, c0);
                    c1 = MFMA16(a1[ks], wf, c1);
                }
#pragma unroll
                for (int r = 0; r < 4; ++r) {
                    w0[r] += qf[nt] * tanh_fast(c0[r] + bkpf[nt]);
                    w1[r] += qf[nt] * tanh_fast(c1[r] + bkpf[nt]);
                }
            }
            // ---- w: reduce over 16 cols within quad + padding mask ----
            int4 mm0 = *(const int4*)(its_lds + ib + r0 + quad * 4);
            int4 mm1 = *(const int4*)(its_lds + ib + r0 + 16 + quad * 4);
            int ma0[4] = {mm0.x, mm0.y, mm0.z, mm0.w};
            int ma1[4] = {mm1.x, mm1.y, mm1.z, mm1.w};
#pragma unroll
            for (int r = 0; r < 4; ++r) {
                float s0 = w0[r], s1 = w1[r];
                s0 += __shfl_xor(s0, 1); s0 += __shfl_xor(s0, 2);
                s0 += __shfl_xor(s0, 4); s0 += __shfl_xor(s0, 8);
                s1 += __shfl_xor(s1, 1); s1 += __shfl_xor(s1, 2);
                s1 += __shfl_xor(s1, 4); s1 += __shfl_xor(s1, 8);
                w0[r] = (ma0[r] > 0) ? s0 : 0.0f;
                w1[r] = (ma1[r] > 0) ? s1 : 0.0f;
            }
            // ---- v_in = item + opin (reuse item frags) ----
            const int od0 = ots_lds[ib + r0 + l15];
            const int od1 = ots_lds[ib + r0 + 16 + l15];
            const float* o0p = opin_table + (size_t)od0 * 128 + quad * 8;
            const float* o1p = opin_table + (size_t)od1 * 128 + quad * 8;
#pragma unroll
            for (int ks = 0; ks < 4; ++ks) {
                a0[ks] = addpack(a0[ks], *(const float4*)(o0p + ks * 32), *(const float4*)(o0p + ks * 32 + 4));
                a1[ks] = addpack(a1[ks], *(const float4*)(o1p + ks * 32), *(const float4*)(o1p + ks * 32 + 4));
            }
            // ---- V pass + weighted aggregation ----
#pragma unroll
            for (int nt = 0; nt < 8; ++nt) {
                f32x4 c0 = {0, 0, 0, 0}, c1 = {0, 0, 0, 0};
#pragma unroll
                for (int ks = 0; ks < 4; ++ks) {
                    const int n = nt * 16 + l15, c = ks * 4 + quad;
                    bf16x8 wf = ((const bf16x8*)wlds)[2048 + (n << 4) + (c ^ (n & 15))];
                    c0 = MFMA16(a0[ks], wf, c0);
                    c1 = MFMA16(a1[ks], wf, c1);
                }
                float acc = 0.0f;
#pragma unroll
                for (int r = 0; r < 4; ++r) {
                    acc += w0[r] * tanh_fast(c0[r] + bvf[nt]);
                    acc += w1[r] * tanh_fast(c1[r] + bvf[nt]);
                }
                o[nt] += acc;
            }
        }
        // ---- reduce o over the 4 row-quads; write 2 cols per lane ----
#pragma unroll
        for (int nt = 0; nt < 8; ++nt) {
            o[nt] += __shfl_xor(o[nt], 16);
            o[nt] += __shfl_xor(o[nt], 32);
        }
        float s0, s1;
        if (quad == 0)      { s0 = o[0]; s1 = o[1]; }
        else if (quad == 1) { s0 = o[2]; s1 = o[3]; }
        else if (quad == 2) { s0 = o[4]; s1 = o[5]; }
        else                { s0 = o[6]; s1 = o[7]; }
        out[u * 128 + (quad * 2 + 0) * 16 + l15] = s0;
        out[u * 128 + (quad * 2 + 1) * 16 + l15] = s1;
    }
}

extern "C" void kernel_launch(void* const* d_in, const int* in_sizes, int n_in,
                              void* d_out, int out_size, void* d_ws, size_t ws_size,
                              hipStream_t stream) {
    const float* item_table = (const float*)d_in[0];
    const float* opin_table = (const float*)d_in[1];
    const float* user_emb   = (const float*)d_in[2];
    const float* attr       = (const float*)d_in[3];
    const float* Wq = (const float*)d_in[4];
    const float* bq = (const float*)d_in[5];
    const float* Wk = (const float*)d_in[6];
    const float* bk = (const float*)d_in[7];
    const float* Wv = (const float*)d_in[8];
    const float* bv = (const float*)d_in[9];
    const int* item_seqs = (const int*)d_in[10];
    const int* opin_seqs = (const int*)d_in[11];
    float* out = (float*)d_out;

    const int U = in_sizes[2] / 128;      // 10000
    const int L = in_sizes[10] / U;       // 50

    float* q_ws   = (float*)d_ws;                    // [U,128] f32
    float* bkp_ws = q_ws + (size_t)U * 128;          // [128] f32
    short* wf_ws  = (short*)(bkp_ws + 128);          // [4096*8] bf16 chunks

    const int qb = (U + 63) / 64;
    finerec_prep<<<qb + 1 + 8, 256, 0, stream>>>(
        user_emb, attr, Wq, bq, Wk, bk, Wv, q_ws, bkp_ws, wf_ws, U);

    const int grid = (U + 8 * UPW - 1) / (8 * UPW);
    finerec_main<<<grid, 512, 0, stream>>>(
        item_table, opin_table, bv, item_seqs, opin_seqs,
        q_ws, bkp_ws, wf_ws, out, U, L);
}

// Round 4
// 539.947 us; speedup vs baseline: 2.6855x; 1.3403x over previous
//
#include <hip/hip_runtime.h>
#include <hip/hip_bf16.h>
#include <stdint.h>

typedef __attribute__((ext_vector_type(8))) short bf16x8;
typedef __attribute__((ext_vector_type(4))) float f32x4;

// ---- bf16 pack via native v_cvt_pk_bf16_f32 (RNE) ----
__device__ __forceinline__ bf16x8 pack2(float4 a, float4 b) {
    union { bf16x8 v; __hip_bfloat162 h[4]; } r;
    r.h[0] = __float22bfloat162_rn(make_float2(a.x, a.y));
    r.h[1] = __float22bfloat162_rn(make_float2(a.z, a.w));
    r.h[2] = __float22bfloat162_rn(make_float2(b.x, b.y));
    r.h[3] = __float22bfloat162_rn(make_float2(b.z, b.w));
    return r.v;
}
__device__ __forceinline__ bf16x8 addpack(bf16x8 ib, float4 a, float4 b) {
    union { bf16x8 v; __hip_bfloat162 h[4]; } s; s.v = ib;
    float2 f0 = __bfloat1622float2(s.h[0]);
    float2 f1 = __bfloat1622float2(s.h[1]);
    float2 f2 = __bfloat1622float2(s.h[2]);
    float2 f3 = __bfloat1622float2(s.h[3]);
    union { bf16x8 v; __hip_bfloat162 h[4]; } r;
    r.h[0] = __float22bfloat162_rn(make_float2(f0.x + a.x, f0.y + a.y));
    r.h[1] = __float22bfloat162_rn(make_float2(f1.x + a.z, f1.y + a.w));
    r.h[2] = __float22bfloat162_rn(make_float2(f2.x + b.x, f2.y + b.y));
    r.h[3] = __float22bfloat162_rn(make_float2(f3.x + b.z, f3.y + b.w));
    return r.v;
}
__device__ __forceinline__ float tanh_fast(float x) {
    float e = __expf(2.0f * x);
    return 1.0f - 2.0f / (e + 1.0f);
}
#define MFMA16(a, b, c) __builtin_amdgcn_mfma_f32_16x16x32_bf16((a), (b), (c), 0, 0, 0)

// =========================================================================
// Kernel 1 (prep): q = tanh(user @ Wq^T + bq) -> q_ws ;
//                  bk' = bk + Wk@attr -> bkp_ws ;
//                  Wk,Wv cast to bf16 swizzled fragment chunks -> wf_ws
// =========================================================================
__global__ void finerec_prep(
    const float* __restrict__ user_emb, const float* __restrict__ attr,
    const float* __restrict__ Wq, const float* __restrict__ bq,
    const float* __restrict__ Wk, const float* __restrict__ bk,
    const float* __restrict__ Wv,
    float* __restrict__ q_ws, float* __restrict__ bkp_ws,
    short* __restrict__ wf_ws, int U)
{
    if (blockIdx.x >= gridDim.x - 8) {           // ---- weight cast: 8 blocks x 512 chunks
        const int bi = blockIdx.x - (gridDim.x - 8);
#pragma unroll
        for (int t = 0; t < 2; ++t) {
            const int g = bi * 512 + t * 256 + threadIdx.x;   // 0..4095
            const int mat = g >> 11, gg = g & 2047, r = gg >> 4, c = gg & 15;
            const float* src = (mat ? Wv : Wk) + r * 128 + c * 8;
            ((bf16x8*)wf_ws)[(mat << 11) + (r << 4) + (c ^ (r & 15))] =
                pack2(*(const float4*)src, *(const float4*)(src + 4));
        }
        return;
    }
    if (blockIdx.x == gridDim.x - 9) {           // ---- bias fold: bk' = bk + Wk @ attr
        int n = threadIdx.x;
        if (n < 128) {
            const float* wr = Wk + n * 128;
            float s = bk[n];
            for (int k = 0; k < 128; k += 4) {
                float4 w4 = *(const float4*)(wr + k);
                float4 a4 = *(const float4*)(attr + k);
                s += w4.x * a4.x + w4.y * a4.y + w4.z * a4.z + w4.w * a4.w;
            }
            bkp_ws[n] = s;
        }
        return;
    }
    // ---- q: 64 users per block (16 per wave) ----
    const int tid = threadIdx.x, wv = tid >> 6, lane = tid & 63;
    const int l15 = lane & 15, quad = lane >> 4;
    const int u0 = (blockIdx.x * 4 + wv) * 16;
    int ur = u0 + l15; if (ur >= U) ur = U - 1;
    const float* up = user_emb + (size_t)ur * 128 + quad * 8;
    bf16x8 af[4];
#pragma unroll
    for (int ks = 0; ks < 4; ++ks)
        af[ks] = pack2(*(const float4*)(up + ks * 32), *(const float4*)(up + ks * 32 + 4));
#pragma unroll
    for (int nt = 0; nt < 8; ++nt) {
        const int n = nt * 16 + l15;
        const float* wp = Wq + n * 128 + quad * 8;
        f32x4 acc = {0, 0, 0, 0};
#pragma unroll
        for (int ks = 0; ks < 4; ++ks) {
            bf16x8 bf = pack2(*(const float4*)(wp + ks * 32), *(const float4*)(wp + ks * 32 + 4));
            acc = MFMA16(af[ks], bf, acc);
        }
        const float bqv = bq[n];
#pragma unroll
        for (int r = 0; r < 4; ++r) {            // C: col = lane&15, row = quad*4+r
            int row = u0 + quad * 4 + r;
            if (row < U) q_ws[row * 128 + nt * 16 + l15] = tanh_fast(acc[r] + bqv);
        }
    }
}

// =========================================================================
// Kernel 2 (main): one user per wave per iteration (UPW iterations),
// ONE 16-row group in flight (lean registers), barrier-free after the
// single LDS weight fill. launch_bounds(512,2) -> empirical 128-VGPR cap.
// =========================================================================
#define UPW 2
__global__ __launch_bounds__(512, 2) void finerec_main(
    const float* __restrict__ item_table, const float* __restrict__ opin_table,
    const float* __restrict__ bv,
    const int* __restrict__ item_seqs, const int* __restrict__ opin_seqs,
    const float* __restrict__ q_ws, const float* __restrict__ bkp_ws,
    const short* __restrict__ wf_ws,
    float* __restrict__ out, int U, int L)
{
    __shared__ __align__(16) short wlds[32768];   // Wk (2048 16B chunks) + Wv (2048), XOR-swizzled
    __shared__ __align__(16) int its_lds[512];
    __shared__ __align__(16) int ots_lds[512];

    const int tid = threadIdx.x;
    const int wv = tid >> 6, lane = tid & 63, l15 = lane & 15, quad = lane >> 4;

    // ---- stage precast weights: straight 16B copy, 8 chunks/thread ----
    const bf16x8* wsrc = (const bf16x8*)wf_ws;
#pragma unroll
    for (int i = 0; i < 8; ++i)
        ((bf16x8*)wlds)[i * 512 + tid] = wsrc[i * 512 + tid];
    __syncthreads();   // the ONLY block barrier

    float bkpf[8], bvf[8];
#pragma unroll
    for (int nt = 0; nt < 8; ++nt) {
        bkpf[nt] = bkp_ws[nt * 16 + l15];
        bvf[nt]  = bv[nt * 16 + l15];
    }
    const int ib = wv * 64;

#pragma unroll 1
    for (int iu = 0; iu < UPW; ++iu) {
        const int u = blockIdx.x * (8 * UPW) + wv * UPW + iu;
        if (u >= U) continue;  // wave-uniform

        {   // stage this wave's indices (intra-wave RAW: ordered by lgkmcnt)
            int vi = 0, vo = 0;
            if (lane < L) { vi = item_seqs[u * L + lane]; vo = opin_seqs[u * L + lane]; }
            its_lds[ib + lane] = vi;
            ots_lds[ib + lane] = vo;
        }
        float qf[8];
#pragma unroll
        for (int nt = 0; nt < 8; ++nt) qf[nt] = q_ws[u * 128 + nt * 16 + l15];

        float o[8] = {0, 0, 0, 0, 0, 0, 0, 0};

#pragma unroll 1
        for (int mp = 0; mp < 4; ++mp) {
            const int r0 = mp * 16;
            const int idx = its_lds[ib + r0 + l15];
            const float* p = item_table + (size_t)idx * 128 + quad * 8;
            bf16x8 a[4];   // A-frags: row = lane&15, k = quad*8+j (+32*ks)
#pragma unroll
            for (int ks = 0; ks < 4; ++ks)
                a[ks] = pack2(*(const float4*)(p + ks * 32), *(const float4*)(p + ks * 32 + 4));

            // ---- K pass (attr folded into bk') ----
            float w[4] = {0, 0, 0, 0};
#pragma unroll
            for (int nt = 0; nt < 8; ++nt) {
                f32x4 c = {0, 0, 0, 0};
#pragma unroll
                for (int ks = 0; ks < 4; ++ks) {
                    const int n = nt * 16 + l15, cc = ks * 4 + quad;
                    bf16x8 wf = ((const bf16x8*)wlds)[(n << 4) + (cc ^ (n & 15))];
                    c = MFMA16(a[ks], wf, c);
                }
#pragma unroll
                for (int r = 0; r < 4; ++r)
                    w[r] += qf[nt] * tanh_fast(c[r] + bkpf[nt]);
            }
            // ---- w: reduce over 16 cols within quad + padding mask ----
            int4 mm = *(const int4*)(its_lds + ib + r0 + quad * 4);
            int ma[4] = {mm.x, mm.y, mm.z, mm.w};
#pragma unroll
            for (int r = 0; r < 4; ++r) {
                float s = w[r];
                s += __shfl_xor(s, 1); s += __shfl_xor(s, 2);
                s += __shfl_xor(s, 4); s += __shfl_xor(s, 8);
                w[r] = (ma[r] > 0) ? s : 0.0f;   // row = r0 + quad*4 + r
            }
            // ---- v_in = item + opin (reuse item frags, no re-gather) ----
            const int od = ots_lds[ib + r0 + l15];
            const float* op = opin_table + (size_t)od * 128 + quad * 8;
#pragma unroll
            for (int ks = 0; ks < 4; ++ks)
                a[ks] = addpack(a[ks], *(const float4*)(op + ks * 32), *(const float4*)(op + ks * 32 + 4));

            // ---- V pass + weighted aggregation ----
#pragma unroll
            for (int nt = 0; nt < 8; ++nt) {
                f32x4 c = {0, 0, 0, 0};
#pragma unroll
                for (int ks = 0; ks < 4; ++ks) {
                    const int n = nt * 16 + l15, cc = ks * 4 + quad;
                    bf16x8 wf = ((const bf16x8*)wlds)[2048 + (n << 4) + (cc ^ (n & 15))];
                    c = MFMA16(a[ks], wf, c);
                }
                float acc = 0.0f;
#pragma unroll
                for (int r = 0; r < 4; ++r)
                    acc += w[r] * tanh_fast(c[r] + bvf[nt]);
                o[nt] += acc;
            }
        }
        // ---- reduce o over the 4 row-quads; write 2 cols per lane ----
#pragma unroll
        for (int nt = 0; nt < 8; ++nt) {
            o[nt] += __shfl_xor(o[nt], 16);
            o[nt] += __shfl_xor(o[nt], 32);
        }
        float s0, s1;
        if (quad == 0)      { s0 = o[0]; s1 = o[1]; }
        else if (quad == 1) { s0 = o[2]; s1 = o[3]; }
        else if (quad == 2) { s0 = o[4]; s1 = o[5]; }
        else                { s0 = o[6]; s1 = o[7]; }
        out[u * 128 + (quad * 2 + 0) * 16 + l15] = s0;
        out[u * 128 + (quad * 2 + 1) * 16 + l15] = s1;
    }
}

extern "C" void kernel_launch(void* const* d_in, const int* in_sizes, int n_in,
                              void* d_out, int out_size, void* d_ws, size_t ws_size,
                              hipStream_t stream) {
    const float* item_table = (const float*)d_in[0];
    const float* opin_table = (const float*)d_in[1];
    const float* user_emb   = (const float*)d_in[2];
    const float* attr       = (const float*)d_in[3];
    const float* Wq = (const float*)d_in[4];
    const float* bq = (const float*)d_in[5];
    const float* Wk = (const float*)d_in[6];
    const float* bk = (const float*)d_in[7];
    const float* Wv = (const float*)d_in[8];
    const float* bv = (const float*)d_in[9];
    const int* item_seqs = (const int*)d_in[10];
    const int* opin_seqs = (const int*)d_in[11];
    float* out = (float*)d_out;

    const int U = in_sizes[2] / 128;      // 10000
    const int L = in_sizes[10] / U;       // 50

    float* q_ws   = (float*)d_ws;                    // [U,128] f32
    float* bkp_ws = q_ws + (size_t)U * 128;          // [128] f32
    short* wf_ws  = (short*)(bkp_ws + 128);          // [4096*8] bf16 chunks

    const int qb = (U + 63) / 64;
    finerec_prep<<<qb + 1 + 8, 256, 0, stream>>>(
        user_emb, attr, Wq, bq, Wk, bk, Wv, q_ws, bkp_ws, wf_ws, U);

    const int grid = (U + 8 * UPW - 1) / (8 * UPW);
    finerec_main<<<grid, 512, 0, stream>>>(
        item_table, opin_table, bv, item_seqs, opin_seqs,
        q_ws, bkp_ws, wf_ws, out, U, L);
}

// Round 5
// 238.727 us; speedup vs baseline: 6.0740x; 2.2618x over previous
//
#include <hip/hip_runtime.h>
#include <hip/hip_bf16.h>
#include <stdint.h>

typedef __attribute__((ext_vector_type(8))) short bf16x8;
typedef __attribute__((ext_vector_type(4))) float f32x4;

// ---- bf16 pack via native v_cvt_pk_bf16_f32 (RNE) ----
__device__ __forceinline__ bf16x8 pack2(float4 a, float4 b) {
    union { bf16x8 v; __hip_bfloat162 h[4]; } r;
    r.h[0] = __float22bfloat162_rn(make_float2(a.x, a.y));
    r.h[1] = __float22bfloat162_rn(make_float2(a.z, a.w));
    r.h[2] = __float22bfloat162_rn(make_float2(b.x, b.y));
    r.h[3] = __float22bfloat162_rn(make_float2(b.z, b.w));
    return r.v;
}
__device__ __forceinline__ bf16x8 addpack(bf16x8 ib, float4 a, float4 b) {
    union { bf16x8 v; __hip_bfloat162 h[4]; } s; s.v = ib;
    float2 f0 = __bfloat1622float2(s.h[0]);
    float2 f1 = __bfloat1622float2(s.h[1]);
    float2 f2 = __bfloat1622float2(s.h[2]);
    float2 f3 = __bfloat1622float2(s.h[3]);
    union { bf16x8 v; __hip_bfloat162 h[4]; } r;
    r.h[0] = __float22bfloat162_rn(make_float2(f0.x + a.x, f0.y + a.y));
    r.h[1] = __float22bfloat162_rn(make_float2(f1.x + a.z, f1.y + a.w));
    r.h[2] = __float22bfloat162_rn(make_float2(f2.x + b.x, f2.y + b.y));
    r.h[3] = __float22bfloat162_rn(make_float2(f3.x + b.z, f3.y + b.w));
    return r.v;
}
__device__ __forceinline__ float tanh_fast(float x) {
    float e = __expf(2.0f * x);
    return 1.0f - 2.0f / (e + 1.0f);
}
#define MFMA16(a, b, c) __builtin_amdgcn_mfma_f32_16x16x32_bf16((a), (b), (c), 0, 0, 0)

// =========================================================================
// Kernel 1 (prep): q = tanh(user @ Wq^T + bq) -> q_ws ;
//                  bk' = bk + Wk@attr -> bkp_ws ;
//                  Wk,Wv cast to bf16 swizzled fragment chunks -> wf_ws
// =========================================================================
__global__ void finerec_prep(
    const float* __restrict__ user_emb, const float* __restrict__ attr,
    const float* __restrict__ Wq, const float* __restrict__ bq,
    const float* __restrict__ Wk, const float* __restrict__ bk,
    const float* __restrict__ Wv,
    float* __restrict__ q_ws, float* __restrict__ bkp_ws,
    short* __restrict__ wf_ws, int U)
{
    if (blockIdx.x >= gridDim.x - 8) {           // ---- weight cast: 8 blocks x 512 chunks
        const int bi = blockIdx.x - (gridDim.x - 8);
#pragma unroll
        for (int t = 0; t < 2; ++t) {
            const int g = bi * 512 + t * 256 + threadIdx.x;   // 0..4095
            const int mat = g >> 11, gg = g & 2047, r = gg >> 4, c = gg & 15;
            const float* src = (mat ? Wv : Wk) + r * 128 + c * 8;
            ((bf16x8*)wf_ws)[(mat << 11) + (r << 4) + (c ^ (r & 15))] =
                pack2(*(const float4*)src, *(const float4*)(src + 4));
        }
        return;
    }
    if (blockIdx.x == gridDim.x - 9) {           // ---- bias fold: bk' = bk + Wk @ attr
        int n = threadIdx.x;
        if (n < 128) {
            const float* wr = Wk + n * 128;
            float s = bk[n];
            for (int k = 0; k < 128; k += 4) {
                float4 w4 = *(const float4*)(wr + k);
                float4 a4 = *(const float4*)(attr + k);
                s += w4.x * a4.x + w4.y * a4.y + w4.z * a4.z + w4.w * a4.w;
            }
            bkp_ws[n] = s;
        }
        return;
    }
    // ---- q: 64 users per block (16 per wave) ----
    const int tid = threadIdx.x, wv = tid >> 6, lane = tid & 63;
    const int l15 = lane & 15, quad = lane >> 4;
    const int u0 = (blockIdx.x * 4 + wv) * 16;
    int ur = u0 + l15; if (ur >= U) ur = U - 1;
    const float* up = user_emb + (size_t)ur * 128 + quad * 8;
    bf16x8 af[4];
#pragma unroll
    for (int ks = 0; ks < 4; ++ks)
        af[ks] = pack2(*(const float4*)(up + ks * 32), *(const float4*)(up + ks * 32 + 4));
#pragma unroll
    for (int nt = 0; nt < 8; ++nt) {
        const int n = nt * 16 + l15;
        const float* wp = Wq + n * 128 + quad * 8;
        f32x4 acc = {0, 0, 0, 0};
#pragma unroll
        for (int ks = 0; ks < 4; ++ks) {
            bf16x8 bf = pack2(*(const float4*)(wp + ks * 32), *(const float4*)(wp + ks * 32 + 4));
            acc = MFMA16(af[ks], bf, acc);
        }
        const float bqv = bq[n];
#pragma unroll
        for (int r = 0; r < 4; ++r) {            // C: col = lane&15, row = quad*4+r
            int row = u0 + quad * 4 + r;
            if (row < U) q_ws[row * 128 + nt * 16 + l15] = tanh_fast(acc[r] + bqv);
        }
    }
}

// =========================================================================
// Kernel 2 (main): one user per wave, rolled nt-loops (bounded in-flight
// LDS frags, no dynamically-indexed register arrays -> zero scratch).
// Two 16-row groups per mp (B-frag feeds 2 MFMAs). One block barrier.
// =========================================================================
__global__ __launch_bounds__(512, 2) void finerec_main(
    const float* __restrict__ item_table, const float* __restrict__ opin_table,
    const float* __restrict__ bv,
    const int* __restrict__ item_seqs, const int* __restrict__ opin_seqs,
    const float* __restrict__ q_ws, const float* __restrict__ bkp_ws,
    const short* __restrict__ wf_ws,
    float* __restrict__ out, int U, int L)
{
    __shared__ __align__(16) short wlds[32768];   // Wk (2048 16B chunks) + Wv (2048), XOR-swizzled
    __shared__ float q_lds[8 * 128];              // per-wave q row
    __shared__ float bkp_lds[128];
    __shared__ float bv_lds[128];

    const int tid = threadIdx.x;
    const int wv = tid >> 6, lane = tid & 63, l15 = lane & 15, quad = lane >> 4;

    // ---- stage precast weights (straight 16B copies) + biases ----
    const bf16x8* wsrc = (const bf16x8*)wf_ws;
    bf16x8* wldsv = (bf16x8*)wlds;
#pragma unroll
    for (int i = 0; i < 8; ++i)
        wldsv[i * 512 + tid] = wsrc[i * 512 + tid];
    if (tid < 128)      bkp_lds[tid] = bkp_ws[tid];
    else if (tid < 256) bv_lds[tid - 128] = bv[tid - 128];
    __syncthreads();   // the ONLY block barrier

    const int u = blockIdx.x * 8 + wv;
    if (u >= U) return;   // wave-uniform, after the barrier

    // per-wave q into LDS (intra-wave RAW, ordered by lgkmcnt)
    q_lds[wv * 128 + lane]      = q_ws[u * 128 + lane];
    q_lds[wv * 128 + 64 + lane] = q_ws[u * 128 + 64 + lane];

    int vi = 0, vo = 0;
    if (lane < L) { vi = item_seqs[u * L + lane]; vo = opin_seqs[u * L + lane]; }
    const unsigned long long mb = __ballot(vi > 0);   // padding mask bits

    float s0 = 0.0f, s1 = 0.0f;   // this lane's 2 output columns

#pragma unroll 1
    for (int mp = 0; mp < 2; ++mp) {
        const int rb = mp * 32;
        const int idx0 = __shfl(vi, rb + l15);
        const int idx1 = __shfl(vi, rb + 16 + l15);
        const float* p0 = item_table + (size_t)idx0 * 128 + quad * 8;
        const float* p1 = item_table + (size_t)idx1 * 128 + quad * 8;
        bf16x8 a0[4], a1[4];   // A-frags: row = lane&15, k = quad*8+j (+32*ks)
#pragma unroll
        for (int ks = 0; ks < 4; ++ks) {
            a0[ks] = pack2(*(const float4*)(p0 + ks * 32), *(const float4*)(p0 + ks * 32 + 4));
            a1[ks] = pack2(*(const float4*)(p1 + ks * 32), *(const float4*)(p1 + ks * 32 + 4));
        }
        // ---- K pass (attr folded into bk'); rolled nt ----
        float w0[4] = {0, 0, 0, 0}, w1[4] = {0, 0, 0, 0};
#pragma unroll 1
        for (int nt = 0; nt < 8; ++nt) {
            const int n = nt * 16 + l15;
            f32x4 c0 = {0, 0, 0, 0}, c1 = {0, 0, 0, 0};
#pragma unroll
            for (int ks = 0; ks < 4; ++ks) {
                bf16x8 wf = wldsv[(n << 4) + ((ks * 4 + quad) ^ (n & 15))];
                c0 = MFMA16(a0[ks], wf, c0);
                c1 = MFMA16(a1[ks], wf, c1);
            }
            const float qv  = q_lds[wv * 128 + nt * 16 + l15];
            const float bkv = bkp_lds[nt * 16 + l15];
#pragma unroll
            for (int r = 0; r < 4; ++r) {
                w0[r] += qv * tanh_fast(c0[r] + bkv);
                w1[r] += qv * tanh_fast(c1[r] + bkv);
            }
        }
        // ---- w: reduce over 16 cols within quad + padding mask ----
#pragma unroll
        for (int r = 0; r < 4; ++r) {
            float t0 = w0[r], t1 = w1[r];
            t0 += __shfl_xor(t0, 1); t0 += __shfl_xor(t0, 2);
            t0 += __shfl_xor(t0, 4); t0 += __shfl_xor(t0, 8);
            t1 += __shfl_xor(t1, 1); t1 += __shfl_xor(t1, 2);
            t1 += __shfl_xor(t1, 4); t1 += __shfl_xor(t1, 8);
            w0[r] = ((mb >> (rb + quad * 4 + r)) & 1ull)      ? t0 : 0.0f;
            w1[r] = ((mb >> (rb + 16 + quad * 4 + r)) & 1ull) ? t1 : 0.0f;
        }
        // ---- v_in = item + opin (reuse item frags, no re-gather) ----
        const int od0 = __shfl(vo, rb + l15);
        const int od1 = __shfl(vo, rb + 16 + l15);
        const float* o0p = opin_table + (size_t)od0 * 128 + quad * 8;
        const float* o1p = opin_table + (size_t)od1 * 128 + quad * 8;
#pragma unroll
        for (int ks = 0; ks < 4; ++ks) {
            a0[ks] = addpack(a0[ks], *(const float4*)(o0p + ks * 32), *(const float4*)(o0p + ks * 32 + 4));
            a1[ks] = addpack(a1[ks], *(const float4*)(o1p + ks * 32), *(const float4*)(o1p + ks * 32 + 4));
        }
        // ---- V pass + weighted aggregation; rolled nt, select-accumulate ----
#pragma unroll 1
        for (int nt = 0; nt < 8; ++nt) {
            const int n = nt * 16 + l15;
            f32x4 c0 = {0, 0, 0, 0}, c1 = {0, 0, 0, 0};
#pragma unroll
            for (int ks = 0; ks < 4; ++ks) {
                bf16x8 wf = wldsv[2048 + (n << 4) + ((ks * 4 + quad) ^ (n & 15))];
                c0 = MFMA16(a0[ks], wf, c0);
                c1 = MFMA16(a1[ks], wf, c1);
            }
            const float bvv = bv_lds[nt * 16 + l15];
            float acc = 0.0f;
#pragma unroll
            for (int r = 0; r < 4; ++r) {
                acc += w0[r] * tanh_fast(c0[r] + bvv);
                acc += w1[r] * tanh_fast(c1[r] + bvv);
            }
            acc += __shfl_xor(acc, 16);   // sum the 4 row-quads
            acc += __shfl_xor(acc, 32);   // -> full col sum in every lane
            const bool mine = (quad == (nt >> 1));
            s0 += (mine && !(nt & 1)) ? acc : 0.0f;
            s1 += (mine &&  (nt & 1)) ? acc : 0.0f;
        }
    }
    out[u * 128 + quad * 32 + l15]      = s0;   // col = (2*quad)*16 + l15
    out[u * 128 + quad * 32 + 16 + l15] = s1;   // col = (2*quad+1)*16 + l15
}

extern "C" void kernel_launch(void* const* d_in, const int* in_sizes, int n_in,
                              void* d_out, int out_size, void* d_ws, size_t ws_size,
                              hipStream_t stream) {
    const float* item_table = (const float*)d_in[0];
    const float* opin_table = (const float*)d_in[1];
    const float* user_emb   = (const float*)d_in[2];
    const float* attr       = (const float*)d_in[3];
    const float* Wq = (const float*)d_in[4];
    const float* bq = (const float*)d_in[5];
    const float* Wk = (const float*)d_in[6];
    const float* bk = (const float*)d_in[7];
    const float* Wv = (const float*)d_in[8];
    const float* bv = (const float*)d_in[9];
    const int* item_seqs = (const int*)d_in[10];
    const int* opin_seqs = (const int*)d_in[11];
    float* out = (float*)d_out;

    const int U = in_sizes[2] / 128;      // 10000
    const int L = in_sizes[10] / U;       // 50

    float* q_ws   = (float*)d_ws;                    // [U,128] f32
    float* bkp_ws = q_ws + (size_t)U * 128;          // [128] f32
    short* wf_ws  = (short*)(bkp_ws + 128);          // [4096*8] bf16 chunks

    const int qb = (U + 63) / 64;
    finerec_prep<<<qb + 1 + 8, 256, 0, stream>>>(
        user_emb, attr, Wq, bq, Wk, bk, Wv, q_ws, bkp_ws, wf_ws, U);

    const int grid = (U + 7) / 8;
    finerec_main<<<grid, 512, 0, stream>>>(
        item_table, opin_table, bv, item_seqs, opin_seqs,
        q_ws, bkp_ws, wf_ws, out, U, L);
}